// Round 1
// baseline (16959.267 us; speedup 1.0000x reference)
//
#include <hip/hip_runtime.h>
#include <hip/hip_bf16.h>
#include <math.h>

#define B_   64
#define T_   512
#define F_   256
#define ENC_ 256
#define P_   128
#define H_   256
#define K_   12
#define INV_TEMP 10.0f

// ---------------- fold: Wc = W_enc @ W_proj, bc = b_enc @ W_proj + b_proj ----
__global__ void fold_kernel(const float* __restrict__ We, const float* __restrict__ be,
                            const float* __restrict__ Wp, const float* __restrict__ bp,
                            float* __restrict__ Wc, float* __restrict__ bc) {
    int f = blockIdx.x;      // 0..256 (256 == bias row)
    int p = threadIdx.x;     // 0..127
    if (f < F_) {
        float a = 0.f;
        for (int e = 0; e < ENC_; e++) a = fmaf(We[f * ENC_ + e], Wp[e * P_ + p], a);
        Wc[f * P_ + p] = a;
    } else {
        float a = bp[p];
        for (int e = 0; e < ENC_; e++) a = fmaf(be[e], Wp[e * P_ + p], a);
        bc[p] = a;
    }
}

// ---------------- generic tiled f32 GEMM: C = A(MxK) @ B(KxN) + bias ---------
// 64x64 tile, 256 threads, 4x4 micro-tile, K-tile 16. Requires K%16==0, N%64==0.
#define TS 64
#define KT 16
__global__ __launch_bounds__(256) void gemm_bias(const float* __restrict__ A,
                                                 const float* __restrict__ Bm,
                                                 const float* __restrict__ bias,
                                                 float* __restrict__ C,
                                                 int M, int N, int K) {
    __shared__ float As[KT][TS + 1];   // As[kk][m], padded (store stride-65 -> no bank conflict)
    __shared__ float Bs[KT][TS];       // Bs[kk][n]
    int tid = threadIdx.x;
    int bm = blockIdx.y * TS, bn = blockIdx.x * TS;
    int tx = tid & 15, ty = tid >> 4;
    float acc[4][4] = {};
    for (int k0 = 0; k0 < K; k0 += KT) {
        #pragma unroll
        for (int i = 0; i < 4; i++) {
            int idx = tid + i * 256;              // 0..1023
            int m = idx >> 4, kk = idx & 15;      // consecutive tid -> consecutive kk (A contiguous in k)
            int gm = bm + m;
            As[kk][m] = (gm < M) ? A[(size_t)gm * K + k0 + kk] : 0.f;
        }
        #pragma unroll
        for (int i = 0; i < 4; i++) {
            int idx = tid + i * 256;
            int kk = idx >> 6, n = idx & 63;      // consecutive tid -> consecutive n (coalesced)
            Bs[kk][n] = Bm[(size_t)(k0 + kk) * N + bn + n];
        }
        __syncthreads();
        #pragma unroll
        for (int kk = 0; kk < KT; kk++) {
            float a0 = As[kk][ty * 4 + 0], a1 = As[kk][ty * 4 + 1];
            float a2 = As[kk][ty * 4 + 2], a3 = As[kk][ty * 4 + 3];
            float4 bq = *(const float4*)&Bs[kk][tx * 4];
            acc[0][0] = fmaf(a0, bq.x, acc[0][0]); acc[0][1] = fmaf(a0, bq.y, acc[0][1]);
            acc[0][2] = fmaf(a0, bq.z, acc[0][2]); acc[0][3] = fmaf(a0, bq.w, acc[0][3]);
            acc[1][0] = fmaf(a1, bq.x, acc[1][0]); acc[1][1] = fmaf(a1, bq.y, acc[1][1]);
            acc[1][2] = fmaf(a1, bq.z, acc[1][2]); acc[1][3] = fmaf(a1, bq.w, acc[1][3]);
            acc[2][0] = fmaf(a2, bq.x, acc[2][0]); acc[2][1] = fmaf(a2, bq.y, acc[2][1]);
            acc[2][2] = fmaf(a2, bq.z, acc[2][2]); acc[2][3] = fmaf(a2, bq.w, acc[2][3]);
            acc[3][0] = fmaf(a3, bq.x, acc[3][0]); acc[3][1] = fmaf(a3, bq.y, acc[3][1]);
            acc[3][2] = fmaf(a3, bq.z, acc[3][2]); acc[3][3] = fmaf(a3, bq.w, acc[3][3]);
        }
        __syncthreads();
    }
    #pragma unroll
    for (int i = 0; i < 4; i++) {
        int gm = bm + ty * 4 + i;
        if (gm >= M) continue;
        #pragma unroll
        for (int j = 0; j < 4; j++) {
            int gn = bn + tx * 4 + j;
            C[(size_t)gm * N + gn] = acc[i][j] + (bias ? bias[gn] : 0.f);
        }
    }
}

// ---------------- GRU scan: one block per batch, 768 threads -----------------
__global__ __launch_bounds__(768) void gru_kernel(const float* __restrict__ gi,
                                                  const float* __restrict__ Wh,
                                                  const float* __restrict__ bhn,
                                                  float* __restrict__ c_seq) {
    int b = blockIdx.x;
    int j = threadIdx.x;                 // 0..767
    __shared__ float hs[H_];
    __shared__ float ghs[3 * H_];
    if (j < H_) hs[j] = 0.f;
    float bh = (j < H_) ? bhn[j] : 0.f;
    __syncthreads();
    const float* gib = gi + (size_t)b * T_ * (3 * H_);
    float* cb = c_seq + (size_t)b * T_ * H_;
    const float* wcol = Wh + j;
    for (int t = 0; t < T_; t++) {
        float acc = 0.f;
        #pragma unroll 16
        for (int i = 0; i < H_; i++) acc = fmaf(hs[i], wcol[(size_t)i * (3 * H_)], acc);
        ghs[j] = acc;
        __syncthreads();
        if (j < H_) {
            float ir  = gib[(size_t)t * (3 * H_) + j];
            float iz  = gib[(size_t)t * (3 * H_) + H_ + j];
            float inn = gib[(size_t)t * (3 * H_) + 2 * H_ + j];
            float r  = 1.f / (1.f + expf(-(ir + ghs[j])));
            float zg = 1.f / (1.f + expf(-(iz + ghs[H_ + j])));
            float n  = tanhf(inn + r * (ghs[2 * H_ + j] + bh));
            float hn = (1.f - zg) * n + zg * hs[j];
            cb[(size_t)t * H_ + j] = hn;
            hs[j] = hn;
        }
        __syncthreads();
    }
}

// ---------------- per-row loss: block = one (b,t) row of logits --------------
__device__ __forceinline__ float wave_sum(float v) {
    #pragma unroll
    for (int o = 32; o > 0; o >>= 1) v += __shfl_down(v, o, 64);
    return v;
}
__device__ __forceinline__ float wave_max(float v) {
    #pragma unroll
    for (int o = 32; o > 0; o >>= 1) v = fmaxf(v, __shfl_down(v, o, 64));
    return v;
}

__global__ __launch_bounds__(256) void loss_kernel(const float* __restrict__ pred,
                                                   const float* __restrict__ z,
                                                   float* __restrict__ accum,
                                                   int k, int Tk, float scale) {
    int t = blockIdx.x;   // 0..Tk-1
    int b = blockIdx.y;
    int tid = threadIdx.x;
    __shared__ float ps[P_];
    __shared__ float red[8];
    if (tid < P_) ps[tid] = pred[((size_t)b * T_ + t) * P_ + tid];
    __syncthreads();

    float myl[2];
    int cnt = 0;
    float maxv = -INFINITY, suml = 0.f;
    for (int i = tid; i < Tk; i += 256) {
        const float* zr = &z[((size_t)b * T_ + (k + i)) * P_];
        float d = 0.f;
        #pragma unroll
        for (int jj = 0; jj < P_; jj += 4) {
            float4 zv = *(const float4*)&zr[jj];
            d = fmaf(ps[jj + 0], zv.x, d);
            d = fmaf(ps[jj + 1], zv.y, d);
            d = fmaf(ps[jj + 2], zv.z, d);
            d = fmaf(ps[jj + 3], zv.w, d);
        }
        float lg = d * INV_TEMP;
        myl[cnt++] = lg;
        maxv = fmaxf(maxv, lg);
        suml += lg;
    }
    // block max
    float m = wave_max(maxv);
    if ((tid & 63) == 0) red[tid >> 6] = m;
    __syncthreads();
    float gmax = fmaxf(fmaxf(red[0], red[1]), fmaxf(red[2], red[3]));
    __syncthreads();
    // sum of exp and sum of logits
    float se = 0.f;
    for (int c = 0; c < cnt; c++) se += expf(myl[c] - gmax);
    float s1 = wave_sum(se), s2 = wave_sum(suml);
    if ((tid & 63) == 0) { red[tid >> 6] = s1; red[4 + (tid >> 6)] = s2; }
    __syncthreads();
    if (tid == 0) {
        float gse = red[0] + red[1] + red[2] + red[3];
        float gsl = red[4] + red[5] + red[6] + red[7];
        float v = gmax + logf(gse) - gsl / (float)Tk;
        atomicAdd(&accum[(b * 513 + t) & 1023], v * scale);
    }
}

__global__ void zero_accum(float* accum) { accum[threadIdx.x] = 0.f; }

__global__ void finalize(const float* __restrict__ accum, float* __restrict__ out) {
    int tid = threadIdx.x;
    __shared__ float red[8];
    float v = 0.f;
    for (int i = tid; i < 1024; i += 256) v += accum[i];
    float s = wave_sum(v);
    if ((tid & 63) == 0) red[tid >> 6] = s;
    __syncthreads();
    if (tid == 0) out[0] = red[0] + red[1] + red[2] + red[3];
}

// ---------------- launch -----------------------------------------------------
extern "C" void kernel_launch(void* const* d_in, const int* in_sizes, int n_in,
                              void* d_out, int out_size, void* d_ws, size_t ws_size,
                              hipStream_t stream) {
    const float* x      = (const float*)d_in[0];
    const float* W_enc  = (const float*)d_in[1];
    const float* b_enc  = (const float*)d_in[2];
    const float* W_proj = (const float*)d_in[3];
    const float* b_proj = (const float*)d_in[4];
    const float* Wi     = (const float*)d_in[5];
    const float* bi     = (const float*)d_in[6];
    const float* Wh     = (const float*)d_in[7];
    const float* bhn    = (const float*)d_in[8];
    const float* Wp     = (const float*)d_in[9];
    const float* bp     = (const float*)d_in[10];
    float* out = (float*)d_out;

    float* ws    = (float*)d_ws;
    float* Wc    = ws;                       // 256*128      = 32768
    float* bc    = Wc + 32768;               // 128
    float* accum = bc + 128;                 // 1024
    float* z     = accum + 1024;             // B*T*P        = 4194304
    float* gi    = z + 4194304;              // B*T*3H       = 25165824
    float* c     = gi + 25165824;            // B*T*H        = 8388608
    float* pred  = c + 8388608;              // B*T*P        = 4194304

    const int MT = B_ * T_;                  // 32768

    zero_accum<<<1, 1024, 0, stream>>>(accum);
    fold_kernel<<<F_ + 1, P_, 0, stream>>>(W_enc, b_enc, W_proj, b_proj, Wc, bc);
    // z = x @ Wc + bc   (M=32768, N=128, K=256)
    gemm_bias<<<dim3(P_ / TS, MT / TS), 256, 0, stream>>>(x, Wc, bc, z, MT, P_, F_);
    // gi = z @ Wi + bi  (M=32768, N=768, K=128)
    gemm_bias<<<dim3(3 * H_ / TS, MT / TS), 256, 0, stream>>>(z, Wi, bi, gi, MT, 3 * H_, P_);
    // GRU scan
    gru_kernel<<<B_, 3 * H_, 0, stream>>>(gi, Wh, bhn, c);
    // per-k: pred = c @ Wp[k-1] + bp[k-1]; then row losses
    for (int k = 1; k <= K_; k++) {
        gemm_bias<<<dim3(P_ / TS, MT / TS), 256, 0, stream>>>(
            c, Wp + (size_t)(k - 1) * H_ * P_, bp + (size_t)(k - 1) * P_, pred, MT, P_, H_);
        int Tk = T_ - k;
        float scale = 1.0f / ((float)K_ * (float)B_ * (float)Tk);
        loss_kernel<<<dim3(Tk, B_), 256, 0, stream>>>(pred, z, accum, k, Tk, scale);
    }
    finalize<<<1, 256, 0, stream>>>(accum, out);
}

// Round 2
// 9388.993 us; speedup vs baseline: 1.8063x; 1.8063x over previous
//
#include <hip/hip_runtime.h>
#include <hip/hip_bf16.h>
#include <math.h>

#define B_   64
#define T_   512
#define F_   256
#define ENC_ 256
#define P_   128
#define H_   256
#define K_   12
#define INV_TEMP 10.0f

// ---------------- fold: Wc = W_enc @ W_proj, bc = b_enc @ W_proj + b_proj ----
__global__ void fold_kernel(const float* __restrict__ We, const float* __restrict__ be,
                            const float* __restrict__ Wp, const float* __restrict__ bp,
                            float* __restrict__ Wc, float* __restrict__ bc) {
    int f = blockIdx.x;      // 0..256 (256 == bias row)
    int p = threadIdx.x;     // 0..127
    if (f < F_) {
        float a = 0.f;
        for (int e = 0; e < ENC_; e++) a = fmaf(We[f * ENC_ + e], Wp[e * P_ + p], a);
        Wc[f * P_ + p] = a;
    } else {
        float a = bp[p];
        for (int e = 0; e < ENC_; e++) a = fmaf(be[e], Wp[e * P_ + p], a);
        bc[p] = a;
    }
}

// ---------------- Wh -> bf16 -------------------------------------------------
__global__ void conv_whb(const float* __restrict__ Wh, __hip_bfloat16* __restrict__ Whb) {
    int i = blockIdx.x * 256 + threadIdx.x;          // 196608 total
    Whb[i] = __float2bfloat16(Wh[i]);
}

// ---------------- generic tiled f32 GEMM: C = A(MxK) @ B(KxN) + bias ---------
#define TS 64
#define KT 16
__global__ __launch_bounds__(256) void gemm_bias(const float* __restrict__ A,
                                                 const float* __restrict__ Bm,
                                                 const float* __restrict__ bias,
                                                 float* __restrict__ C,
                                                 int M, int N, int K) {
    __shared__ float As[KT][TS + 1];
    __shared__ float Bs[KT][TS];
    int tid = threadIdx.x;
    int bm = blockIdx.y * TS, bn = blockIdx.x * TS;
    int tx = tid & 15, ty = tid >> 4;
    float acc[4][4] = {};
    for (int k0 = 0; k0 < K; k0 += KT) {
        #pragma unroll
        for (int i = 0; i < 4; i++) {
            int idx = tid + i * 256;
            int m = idx >> 4, kk = idx & 15;
            int gm = bm + m;
            As[kk][m] = (gm < M) ? A[(size_t)gm * K + k0 + kk] : 0.f;
        }
        #pragma unroll
        for (int i = 0; i < 4; i++) {
            int idx = tid + i * 256;
            int kk = idx >> 6, n = idx & 63;
            Bs[kk][n] = Bm[(size_t)(k0 + kk) * N + bn + n];
        }
        __syncthreads();
        #pragma unroll
        for (int kk = 0; kk < KT; kk++) {
            float a0 = As[kk][ty * 4 + 0], a1 = As[kk][ty * 4 + 1];
            float a2 = As[kk][ty * 4 + 2], a3 = As[kk][ty * 4 + 3];
            float4 bq = *(const float4*)&Bs[kk][tx * 4];
            acc[0][0] = fmaf(a0, bq.x, acc[0][0]); acc[0][1] = fmaf(a0, bq.y, acc[0][1]);
            acc[0][2] = fmaf(a0, bq.z, acc[0][2]); acc[0][3] = fmaf(a0, bq.w, acc[0][3]);
            acc[1][0] = fmaf(a1, bq.x, acc[1][0]); acc[1][1] = fmaf(a1, bq.y, acc[1][1]);
            acc[1][2] = fmaf(a1, bq.z, acc[1][2]); acc[1][3] = fmaf(a1, bq.w, acc[1][3]);
            acc[2][0] = fmaf(a2, bq.x, acc[2][0]); acc[2][1] = fmaf(a2, bq.y, acc[2][1]);
            acc[2][2] = fmaf(a2, bq.z, acc[2][2]); acc[2][3] = fmaf(a2, bq.w, acc[2][3]);
            acc[3][0] = fmaf(a3, bq.x, acc[3][0]); acc[3][1] = fmaf(a3, bq.y, acc[3][1]);
            acc[3][2] = fmaf(a3, bq.z, acc[3][2]); acc[3][3] = fmaf(a3, bq.w, acc[3][3]);
        }
        __syncthreads();
    }
    #pragma unroll
    for (int i = 0; i < 4; i++) {
        int gm = bm + ty * 4 + i;
        if (gm >= M) continue;
        #pragma unroll
        for (int j = 0; j < 4; j++) {
            int gn = bn + tx * 4 + j;
            C[(size_t)gm * N + gn] = acc[i][j] + (bias ? bias[gn] : 0.f);
        }
    }
}

// ---------------- GRU scan: one block per batch, 768 threads -----------------
// Wh in bf16; first RCACHE rows cached pre-converted in VGPRs, rest streamed
// from L2 (240 KB/step instead of 768 KB fp32).
#define RCACHE 96
__global__ __launch_bounds__(768, 3) void gru_kernel(const float* __restrict__ gi,
                                                     const __hip_bfloat16* __restrict__ Whb,
                                                     const float* __restrict__ bhn,
                                                     float* __restrict__ c_seq) {
    int b = blockIdx.x;
    int j = threadIdx.x;                 // 0..767
    __shared__ float hs[H_];
    __shared__ float ghs[3 * H_];
    if (j < H_) hs[j] = 0.f;
    float bh = (j < H_) ? bhn[j] : 0.f;
    const __hip_bfloat16* wcol = Whb + j;
    float wreg[RCACHE];
    #pragma unroll
    for (int i = 0; i < RCACHE; i++) wreg[i] = __bfloat162float(wcol[(size_t)i * (3 * H_)]);
    __syncthreads();
    const float* gib = gi + (size_t)b * T_ * (3 * H_);
    float* cb = c_seq + (size_t)b * T_ * H_;
    for (int t = 0; t < T_; t++) {
        float a0 = 0.f, a1 = 0.f, a2 = 0.f, a3 = 0.f;
        #pragma unroll
        for (int i = 0; i < RCACHE; i += 4) {
            a0 = fmaf(hs[i + 0], wreg[i + 0], a0);
            a1 = fmaf(hs[i + 1], wreg[i + 1], a1);
            a2 = fmaf(hs[i + 2], wreg[i + 2], a2);
            a3 = fmaf(hs[i + 3], wreg[i + 3], a3);
        }
        #pragma unroll 8
        for (int i = RCACHE; i < H_; i += 4) {
            float w0 = __bfloat162float(wcol[(size_t)(i + 0) * (3 * H_)]);
            float w1 = __bfloat162float(wcol[(size_t)(i + 1) * (3 * H_)]);
            float w2 = __bfloat162float(wcol[(size_t)(i + 2) * (3 * H_)]);
            float w3 = __bfloat162float(wcol[(size_t)(i + 3) * (3 * H_)]);
            a0 = fmaf(hs[i + 0], w0, a0);
            a1 = fmaf(hs[i + 1], w1, a1);
            a2 = fmaf(hs[i + 2], w2, a2);
            a3 = fmaf(hs[i + 3], w3, a3);
        }
        ghs[j] = (a0 + a1) + (a2 + a3);
        __syncthreads();
        if (j < H_) {
            float ir  = gib[(size_t)t * (3 * H_) + j];
            float iz  = gib[(size_t)t * (3 * H_) + H_ + j];
            float inn = gib[(size_t)t * (3 * H_) + 2 * H_ + j];
            float r  = 1.f / (1.f + expf(-(ir + ghs[j])));
            float zg = 1.f / (1.f + expf(-(iz + ghs[H_ + j])));
            float n  = tanhf(inn + r * (ghs[2 * H_ + j] + bh));
            float hn = (1.f - zg) * n + zg * hs[j];
            cb[(size_t)t * H_ + j] = hn;
            hs[j] = hn;
        }
        __syncthreads();
    }
}

// ---------------- transpose z (BxTxP) -> zt (BxPxT) --------------------------
__global__ __launch_bounds__(256) void transpose_z(const float* __restrict__ z,
                                                   float* __restrict__ zt) {
    __shared__ float tile[32][33];
    int b = blockIdx.z;
    int t0 = blockIdx.x * 32, d0 = blockIdx.y * 32;
    int tx = threadIdx.x & 31, ty = threadIdx.x >> 5;   // 32 x 8
    #pragma unroll
    for (int i = 0; i < 32; i += 8)
        tile[ty + i][tx] = z[((size_t)b * T_ + t0 + ty + i) * P_ + d0 + tx];
    __syncthreads();
    #pragma unroll
    for (int i = 0; i < 32; i += 8)
        zt[((size_t)b * P_ + d0 + ty + i) * T_ + t0 + tx] = tile[tx][ty + i];
}

// ---------------- wave helpers ----------------------------------------------
__device__ __forceinline__ float wave_sum(float v) {
    #pragma unroll
    for (int o = 32; o > 0; o >>= 1) v += __shfl_down(v, o, 64);
    return v;
}

// ---------------- flash loss: 64-row x 64-col logit tiles, online LSE --------
// grid (ceil(Tk/64), B). One atomicAdd per block.
__global__ __launch_bounds__(256) void loss_flash(const float* __restrict__ pred,
                                                  const float* __restrict__ zt,
                                                  float* __restrict__ accum,
                                                  int k, int Tk, float scale) {
    __shared__ float As[KT][TS + 1];
    __shared__ float Bs[KT][TS];
    __shared__ float red[4];
    int b = blockIdx.y;
    int t0 = blockIdx.x * TS;
    int tid = threadIdx.x;
    int tx = tid & 15, ty = tid >> 4;
    const float* predb = pred + (size_t)b * T_ * P_;
    const float* ztb   = zt + (size_t)b * P_ * T_;

    float m[4], s[4], sl[4];
    #pragma unroll
    for (int i = 0; i < 4; i++) { m[i] = -INFINITY; s[i] = 0.f; sl[i] = 0.f; }

    for (int ct = 0; ct < Tk; ct += TS) {
        float acc[4][4] = {};
        for (int k0 = 0; k0 < P_; k0 += KT) {
            #pragma unroll
            for (int i = 0; i < 4; i++) {
                int idx = tid + i * 256;
                int mm = idx >> 4, kk = idx & 15;
                int gr = t0 + mm;
                As[kk][mm] = (gr < Tk) ? predb[(size_t)gr * P_ + k0 + kk] : 0.f;
            }
            #pragma unroll
            for (int i = 0; i < 4; i++) {
                int idx = tid + i * 256;
                int kk = idx >> 6, n = idx & 63;
                int gc = ct + n;
                Bs[kk][n] = (gc < Tk) ? ztb[(size_t)(k0 + kk) * T_ + k + gc] : 0.f;
            }
            __syncthreads();
            #pragma unroll
            for (int kk = 0; kk < KT; kk++) {
                float a0 = As[kk][ty * 4 + 0], a1 = As[kk][ty * 4 + 1];
                float a2 = As[kk][ty * 4 + 2], a3 = As[kk][ty * 4 + 3];
                float4 bq = *(const float4*)&Bs[kk][tx * 4];
                acc[0][0] = fmaf(a0, bq.x, acc[0][0]); acc[0][1] = fmaf(a0, bq.y, acc[0][1]);
                acc[0][2] = fmaf(a0, bq.z, acc[0][2]); acc[0][3] = fmaf(a0, bq.w, acc[0][3]);
                acc[1][0] = fmaf(a1, bq.x, acc[1][0]); acc[1][1] = fmaf(a1, bq.y, acc[1][1]);
                acc[1][2] = fmaf(a1, bq.z, acc[1][2]); acc[1][3] = fmaf(a1, bq.w, acc[1][3]);
                acc[2][0] = fmaf(a2, bq.x, acc[2][0]); acc[2][1] = fmaf(a2, bq.y, acc[2][1]);
                acc[2][2] = fmaf(a2, bq.z, acc[2][2]); acc[2][3] = fmaf(a2, bq.w, acc[2][3]);
                acc[3][0] = fmaf(a3, bq.x, acc[3][0]); acc[3][1] = fmaf(a3, bq.y, acc[3][1]);
                acc[3][2] = fmaf(a3, bq.z, acc[3][2]); acc[3][3] = fmaf(a3, bq.w, acc[3][3]);
            }
            __syncthreads();
        }
        // online LSE update over this 64-col tile
        #pragma unroll
        for (int i = 0; i < 4; i++) {
            float l[4];
            float tmax = -INFINITY, tsum = 0.f;
            #pragma unroll
            for (int j = 0; j < 4; j++) {
                int gc = ct + tx * 4 + j;
                bool valid = gc < Tk;
                l[j] = valid ? acc[i][j] * INV_TEMP : -INFINITY;
                tmax = fmaxf(tmax, l[j]);
                tsum += valid ? l[j] : 0.f;
            }
            #pragma unroll
            for (int o = 1; o < 16; o <<= 1) {
                float ot = __shfl_xor(tmax, o, 64);
                tmax = fmaxf(tmax, ot);
            }
            float mnew = fmaxf(m[i], tmax);
            float e = 0.f;
            #pragma unroll
            for (int j = 0; j < 4; j++) e += expf(l[j] - mnew);
            #pragma unroll
            for (int o = 1; o < 16; o <<= 1) {
                e    += __shfl_xor(e, o, 64);
                tsum += __shfl_xor(tsum, o, 64);
            }
            s[i]  = s[i] * expf(m[i] - mnew) + e;
            m[i]  = mnew;
            sl[i] += tsum;
        }
    }
    // per-row value: LSE - mean(logits); sum valid rows
    float bs = 0.f;
    #pragma unroll
    for (int i = 0; i < 4; i++) {
        int gr = t0 + ty * 4 + i;
        if (gr < Tk) bs += m[i] + logf(s[i]) - sl[i] / (float)Tk;
    }
    if (tx != 0) bs = 0.f;          // value replicated across the 16 tx lanes
    bs = wave_sum(bs);
    if ((tid & 63) == 0) red[tid >> 6] = bs;
    __syncthreads();
    if (tid == 0)
        atomicAdd(&accum[(blockIdx.x * 67 + b) & 1023],
                  (red[0] + red[1] + red[2] + red[3]) * scale);
}

__global__ void zero_accum(float* accum) { accum[threadIdx.x] = 0.f; }

__global__ void finalize(const float* __restrict__ accum, float* __restrict__ out) {
    int tid = threadIdx.x;
    __shared__ float red[4];
    float v = 0.f;
    for (int i = tid; i < 1024; i += 256) v += accum[i];
    float sres = wave_sum(v);
    if ((tid & 63) == 0) red[tid >> 6] = sres;
    __syncthreads();
    if (tid == 0) out[0] = red[0] + red[1] + red[2] + red[3];
}

// ---------------- launch -----------------------------------------------------
extern "C" void kernel_launch(void* const* d_in, const int* in_sizes, int n_in,
                              void* d_out, int out_size, void* d_ws, size_t ws_size,
                              hipStream_t stream) {
    const float* x      = (const float*)d_in[0];
    const float* W_enc  = (const float*)d_in[1];
    const float* b_enc  = (const float*)d_in[2];
    const float* W_proj = (const float*)d_in[3];
    const float* b_proj = (const float*)d_in[4];
    const float* Wi     = (const float*)d_in[5];
    const float* bi     = (const float*)d_in[6];
    const float* Wh     = (const float*)d_in[7];
    const float* bhn    = (const float*)d_in[8];
    const float* Wp     = (const float*)d_in[9];
    const float* bp     = (const float*)d_in[10];
    float* out = (float*)d_out;

    float* ws    = (float*)d_ws;
    float* Wc    = ws;                        // 32768
    float* bc    = Wc + 32768;                // 128
    float* accum = bc + 128;                  // 1024
    __hip_bfloat16* Whb = (__hip_bfloat16*)(accum + 1024);   // 196608 bf16 = 98304 float-slots
    float* z     = accum + 1024 + 98304;      // B*T*P   = 4194304
    float* gi    = z + 4194304;               // B*T*3H  = 25165824
    float* c     = gi + 25165824;             // B*T*H   = 8388608
    // zt and pred alias gi (gi is dead after the GRU scan)
    float* zt    = gi;                        // B*P*T   = 4194304
    float* pred  = gi + 4194304;              // B*T*P   = 4194304

    const int MT = B_ * T_;                   // 32768

    zero_accum<<<1, 1024, 0, stream>>>(accum);
    fold_kernel<<<F_ + 1, P_, 0, stream>>>(W_enc, b_enc, W_proj, b_proj, Wc, bc);
    conv_whb<<<(H_ * 3 * H_) / 256, 256, 0, stream>>>(Wh, Whb);
    // z = x @ Wc + bc   (M=32768, N=128, K=256)
    gemm_bias<<<dim3(P_ / TS, MT / TS), 256, 0, stream>>>(x, Wc, bc, z, MT, P_, F_);
    // gi = z @ Wi + bi  (M=32768, N=768, K=128)
    gemm_bias<<<dim3(3 * H_ / TS, MT / TS), 256, 0, stream>>>(z, Wi, bi, gi, MT, 3 * H_, P_);
    // GRU scan
    gru_kernel<<<B_, 3 * H_, 0, stream>>>(gi, Whb, bhn, c);
    // transpose z for coalesced column access in the flash loss
    transpose_z<<<dim3(T_ / 32, P_ / 32, B_), 256, 0, stream>>>(z, zt);
    // per-k: pred = c @ Wp[k-1] + bp[k-1]; flash loss
    for (int k = 1; k <= K_; k++) {
        gemm_bias<<<dim3(P_ / TS, MT / TS), 256, 0, stream>>>(
            c, Wp + (size_t)(k - 1) * H_ * P_, bp + (size_t)(k - 1) * P_, pred, MT, P_, H_);
        int Tk = T_ - k;
        float scale = 1.0f / ((float)K_ * (float)B_ * (float)Tk);
        loss_flash<<<dim3((Tk + TS - 1) / TS, B_), 256, 0, stream>>>(pred, zt, accum, k, Tk, scale);
    }
    finalize<<<1, 256, 0, stream>>>(accum, out);
}

// Round 3
// 7781.494 us; speedup vs baseline: 2.1794x; 1.2066x over previous
//
#include <hip/hip_runtime.h>
#include <hip/hip_bf16.h>
#include <math.h>

#define B_   64
#define T_   512
#define F_   256
#define ENC_ 256
#define P_   128
#define H_   256
#define K_   12
#define INV_TEMP 10.0f

// ---------------- helpers ----------------------------------------------------
__device__ __forceinline__ float bflo(unsigned int u) { return __uint_as_float(u << 16); }
__device__ __forceinline__ float bfhi(unsigned int u) { return __uint_as_float(u & 0xffff0000u); }
__device__ __forceinline__ unsigned short f2bf(float f) {   // RNE
    unsigned int u = __float_as_uint(f);
    unsigned int r = (u + 0x7fffu + ((u >> 16) & 1u)) >> 16;
    return (unsigned short)r;
}
__device__ __forceinline__ float wave_sum(float v) {
    #pragma unroll
    for (int o = 32; o > 0; o >>= 1) v += __shfl_down(v, o, 64);
    return v;
}

// ---------------- fold: Wc = W_enc @ W_proj, bc = b_enc @ W_proj + b_proj ----
__global__ void fold_kernel(const float* __restrict__ We, const float* __restrict__ be,
                            const float* __restrict__ Wp, const float* __restrict__ bp,
                            float* __restrict__ Wc, float* __restrict__ bc) {
    int f = blockIdx.x;      // 0..256 (256 == bias row)
    int p = threadIdx.x;     // 0..127
    if (f < F_) {
        float a = 0.f;
        for (int e = 0; e < ENC_; e++) a = fmaf(We[f * ENC_ + e], Wp[e * P_ + p], a);
        Wc[f * P_ + p] = a;
    } else {
        float a = bp[p];
        for (int e = 0; e < ENC_; e++) a = fmaf(be[e], Wp[e * P_ + p], a);
        bc[p] = a;
    }
}

// ---------------- Wh -> packed bf16: Whp[i4*768+j] = rows 4i4..4i4+3, col j --
__global__ void conv_whp(const float* __restrict__ Wh, uint2* __restrict__ Whp) {
    int idx = blockIdx.x * 256 + threadIdx.x;        // 49152 total
    int i4 = idx / 768, j = idx % 768;
    unsigned int r0 = f2bf(Wh[(size_t)(4 * i4 + 0) * 768 + j]);
    unsigned int r1 = f2bf(Wh[(size_t)(4 * i4 + 1) * 768 + j]);
    unsigned int r2 = f2bf(Wh[(size_t)(4 * i4 + 2) * 768 + j]);
    unsigned int r3 = f2bf(Wh[(size_t)(4 * i4 + 3) * 768 + j]);
    Whp[idx] = make_uint2(r0 | (r1 << 16), r2 | (r3 << 16));
}

// ---------------- generic tiled f32 GEMM: C = A(MxK) @ B(KxN) + bias ---------
#define TS 64
#define KT 16
__global__ __launch_bounds__(256) void gemm_bias(const float* __restrict__ A,
                                                 const float* __restrict__ Bm,
                                                 const float* __restrict__ bias,
                                                 float* __restrict__ C,
                                                 int M, int N, int K) {
    __shared__ float As[KT][TS + 1];
    __shared__ float Bs[KT][TS];
    int tid = threadIdx.x;
    int bm = blockIdx.y * TS, bn = blockIdx.x * TS;
    int tx = tid & 15, ty = tid >> 4;
    float acc[4][4] = {};
    for (int k0 = 0; k0 < K; k0 += KT) {
        #pragma unroll
        for (int i = 0; i < 4; i++) {
            int idx = tid + i * 256;
            int m = idx >> 4, kk = idx & 15;
            int gm = bm + m;
            As[kk][m] = (gm < M) ? A[(size_t)gm * K + k0 + kk] : 0.f;
        }
        #pragma unroll
        for (int i = 0; i < 4; i++) {
            int idx = tid + i * 256;
            int kk = idx >> 6, n = idx & 63;
            Bs[kk][n] = Bm[(size_t)(k0 + kk) * N + bn + n];
        }
        __syncthreads();
        #pragma unroll
        for (int kk = 0; kk < KT; kk++) {
            float a0 = As[kk][ty * 4 + 0], a1 = As[kk][ty * 4 + 1];
            float a2 = As[kk][ty * 4 + 2], a3 = As[kk][ty * 4 + 3];
            float4 bq = *(const float4*)&Bs[kk][tx * 4];
            acc[0][0] = fmaf(a0, bq.x, acc[0][0]); acc[0][1] = fmaf(a0, bq.y, acc[0][1]);
            acc[0][2] = fmaf(a0, bq.z, acc[0][2]); acc[0][3] = fmaf(a0, bq.w, acc[0][3]);
            acc[1][0] = fmaf(a1, bq.x, acc[1][0]); acc[1][1] = fmaf(a1, bq.y, acc[1][1]);
            acc[1][2] = fmaf(a1, bq.z, acc[1][2]); acc[1][3] = fmaf(a1, bq.w, acc[1][3]);
            acc[2][0] = fmaf(a2, bq.x, acc[2][0]); acc[2][1] = fmaf(a2, bq.y, acc[2][1]);
            acc[2][2] = fmaf(a2, bq.z, acc[2][2]); acc[2][3] = fmaf(a2, bq.w, acc[2][3]);
            acc[3][0] = fmaf(a3, bq.x, acc[3][0]); acc[3][1] = fmaf(a3, bq.y, acc[3][1]);
            acc[3][2] = fmaf(a3, bq.z, acc[3][2]); acc[3][3] = fmaf(a3, bq.w, acc[3][3]);
        }
        __syncthreads();
    }
    #pragma unroll
    for (int i = 0; i < 4; i++) {
        int gm = bm + ty * 4 + i;
        if (gm >= M) continue;
        #pragma unroll
        for (int j = 0; j < 4; j++) {
            int gn = bn + tx * 4 + j;
            C[(size_t)gm * N + gn] = acc[i][j] + (bias ? bias[gn] : 0.f);
        }
    }
}

// ---------------- GRU scan: one block per batch, 768 threads -----------------
// Whp: bf16, 4 rows packed per uint2. First NREG groups cached in VGPRs
// (vector-typed, fully unrolled => no spill; launch_bounds(768,1) gives the
// allocator the full budget). Remaining 64-NREG groups streamed from L2
// (96 KB/step instead of 768 KB fp32).
#define NREG 48
__global__ __launch_bounds__(768, 1) void gru_kernel(const float* __restrict__ gi,
                                                     const uint2* __restrict__ Whp,
                                                     const float* __restrict__ bhn,
                                                     float* __restrict__ c_seq) {
    int b = blockIdx.x;
    int j = threadIdx.x;                 // 0..767
    __shared__ float hs[H_];
    __shared__ float ghs[3 * H_];
    if (j < H_) hs[j] = 0.f;
    float bh = (j < H_) ? bhn[j] : 0.f;
    const uint2* wcol = Whp + j;
    uint2 wreg[NREG];
    #pragma unroll
    for (int i = 0; i < NREG; i++) wreg[i] = wcol[(size_t)i * 768];
    __syncthreads();
    const float* gib = gi + (size_t)b * T_ * 768;
    float* cb = c_seq + (size_t)b * T_ * H_;
    const float4* hs4 = (const float4*)hs;
    for (int t = 0; t < T_; t++) {
        float a0 = 0.f, a1 = 0.f, a2 = 0.f, a3 = 0.f;
        #pragma unroll
        for (int i = 0; i < NREG; i++) {
            float4 hv = hs4[i];
            a0 = fmaf(hv.x, bflo(wreg[i].x), a0);
            a1 = fmaf(hv.y, bfhi(wreg[i].x), a1);
            a2 = fmaf(hv.z, bflo(wreg[i].y), a2);
            a3 = fmaf(hv.w, bfhi(wreg[i].y), a3);
        }
        #pragma unroll 8
        for (int i = NREG; i < 64; i++) {
            uint2 w = wcol[(size_t)i * 768];
            float4 hv = hs4[i];
            a0 = fmaf(hv.x, bflo(w.x), a0);
            a1 = fmaf(hv.y, bfhi(w.x), a1);
            a2 = fmaf(hv.z, bflo(w.y), a2);
            a3 = fmaf(hv.w, bfhi(w.y), a3);
        }
        ghs[j] = (a0 + a1) + (a2 + a3);
        __syncthreads();
        if (j < H_) {
            float ir  = gib[(size_t)t * 768 + j];
            float iz  = gib[(size_t)t * 768 + H_ + j];
            float inn = gib[(size_t)t * 768 + 2 * H_ + j];
            float r  = 1.f / (1.f + expf(-(ir + ghs[j])));
            float zg = 1.f / (1.f + expf(-(iz + ghs[H_ + j])));
            float n  = tanhf(inn + r * (ghs[2 * H_ + j] + bh));
            float hn = (1.f - zg) * n + zg * hs[j];
            cb[(size_t)t * H_ + j] = hn;
            hs[j] = hn;
        }
        __syncthreads();
    }
}

// ---------------- transpose z (BxTxP) -> zt (BxPxT) --------------------------
__global__ __launch_bounds__(256) void transpose_z(const float* __restrict__ z,
                                                   float* __restrict__ zt) {
    __shared__ float tile[32][33];
    int b = blockIdx.z;
    int t0 = blockIdx.x * 32, d0 = blockIdx.y * 32;
    int tx = threadIdx.x & 31, ty = threadIdx.x >> 5;   // 32 x 8
    #pragma unroll
    for (int i = 0; i < 32; i += 8)
        tile[ty + i][tx] = z[((size_t)b * T_ + t0 + ty + i) * P_ + d0 + tx];
    __syncthreads();
    #pragma unroll
    for (int i = 0; i < 32; i += 8)
        zt[((size_t)b * P_ + d0 + ty + i) * T_ + t0 + tx] = tile[tx][ty + i];
}

// ---------------- fused loss: pred tile GEMM + flash LSE, all k in one grid --
// grid (8, B, K). Block (t-tile, b, k-1):
//   phase 1: Pst[128][64] = (c[b, t0:t0+64] @ Wp[k-1] + bp[k-1])^T   (K=256)
//   phase 2: flash over 64-col z tiles, online LSE per row
__global__ __launch_bounds__(256) void loss_fused(const float* __restrict__ c,
                                                  const float* __restrict__ Wp,
                                                  const float* __restrict__ bp,
                                                  const float* __restrict__ zt,
                                                  float* __restrict__ accum) {
    __shared__ float Pst[P_][TS + 1];    // pred^T: [k-dim 128][row 64]
    __shared__ float As[KT][TS + 1];
    __shared__ float Bs[KT][2 * TS];     // phase1: Wp tile [16][128]; phase2: z tile [16][64]
    __shared__ float red[4];
    int k  = blockIdx.z + 1;
    int b  = blockIdx.y;
    int t0 = blockIdx.x * TS;
    int Tk = T_ - k;
    int tid = threadIdx.x;

    // ---- phase 1: pred tile (64 rows x 128 cols), microtile 4x8 -------------
    {
        int tx = tid & 15, ty = tid >> 4;   // tx: 16 col-groups of 8, ty: 16 row-groups of 4
        float acc[4][8] = {};
        const float* cb  = c + ((size_t)b * T_ + t0) * H_;
        const float* wpk = Wp + (size_t)(k - 1) * H_ * P_;
        for (int k0 = 0; k0 < H_; k0 += KT) {
            #pragma unroll
            for (int i = 0; i < 4; i++) {
                int idx = tid + i * 256;
                int mm = idx >> 4, kk = idx & 15;
                As[kk][mm] = cb[(size_t)mm * H_ + k0 + kk];
            }
            #pragma unroll
            for (int i = 0; i < 8; i++) {
                int idx = tid + i * 256;
                int kk = idx >> 7, n = idx & 127;
                Bs[kk][n] = wpk[(size_t)(k0 + kk) * P_ + n];
            }
            __syncthreads();
            #pragma unroll
            for (int kk = 0; kk < KT; kk++) {
                float a0 = As[kk][ty * 4 + 0], a1 = As[kk][ty * 4 + 1];
                float a2 = As[kk][ty * 4 + 2], a3 = As[kk][ty * 4 + 3];
                float4 b0 = *(const float4*)&Bs[kk][tx * 8];
                float4 b1 = *(const float4*)&Bs[kk][tx * 8 + 4];
                acc[0][0] = fmaf(a0, b0.x, acc[0][0]); acc[0][1] = fmaf(a0, b0.y, acc[0][1]);
                acc[0][2] = fmaf(a0, b0.z, acc[0][2]); acc[0][3] = fmaf(a0, b0.w, acc[0][3]);
                acc[0][4] = fmaf(a0, b1.x, acc[0][4]); acc[0][5] = fmaf(a0, b1.y, acc[0][5]);
                acc[0][6] = fmaf(a0, b1.z, acc[0][6]); acc[0][7] = fmaf(a0, b1.w, acc[0][7]);
                acc[1][0] = fmaf(a1, b0.x, acc[1][0]); acc[1][1] = fmaf(a1, b0.y, acc[1][1]);
                acc[1][2] = fmaf(a1, b0.z, acc[1][2]); acc[1][3] = fmaf(a1, b0.w, acc[1][3]);
                acc[1][4] = fmaf(a1, b1.x, acc[1][4]); acc[1][5] = fmaf(a1, b1.y, acc[1][5]);
                acc[1][6] = fmaf(a1, b1.z, acc[1][6]); acc[1][7] = fmaf(a1, b1.w, acc[1][7]);
                acc[2][0] = fmaf(a2, b0.x, acc[2][0]); acc[2][1] = fmaf(a2, b0.y, acc[2][1]);
                acc[2][2] = fmaf(a2, b0.z, acc[2][2]); acc[2][3] = fmaf(a2, b0.w, acc[2][3]);
                acc[2][4] = fmaf(a2, b1.x, acc[2][4]); acc[2][5] = fmaf(a2, b1.y, acc[2][5]);
                acc[2][6] = fmaf(a2, b1.z, acc[2][6]); acc[2][7] = fmaf(a2, b1.w, acc[2][7]);
                acc[3][0] = fmaf(a3, b0.x, acc[3][0]); acc[3][1] = fmaf(a3, b0.y, acc[3][1]);
                acc[3][2] = fmaf(a3, b0.z, acc[3][2]); acc[3][3] = fmaf(a3, b0.w, acc[3][3]);
                acc[3][4] = fmaf(a3, b1.x, acc[3][4]); acc[3][5] = fmaf(a3, b1.y, acc[3][5]);
                acc[3][6] = fmaf(a3, b1.z, acc[3][6]); acc[3][7] = fmaf(a3, b1.w, acc[3][7]);
            }
            __syncthreads();
        }
        #pragma unroll
        for (int jj = 0; jj < 8; jj++) {
            float bias = bp[(size_t)(k - 1) * P_ + tx * 8 + jj];
            #pragma unroll
            for (int i = 0; i < 4; i++)
                Pst[tx * 8 + jj][ty * 4 + i] = acc[i][jj] + bias;
        }
    }
    __syncthreads();

    // ---- phase 2: flash over column tiles -----------------------------------
    int tx = tid & 15, ty = tid >> 4;
    float m[4], s[4], sl[4];
    #pragma unroll
    for (int i = 0; i < 4; i++) { m[i] = -INFINITY; s[i] = 0.f; sl[i] = 0.f; }
    const float* ztb = zt + (size_t)b * P_ * T_;

    for (int ct = 0; ct < Tk; ct += TS) {
        float acc[4][4] = {};
        for (int k0 = 0; k0 < P_; k0 += KT) {
            #pragma unroll
            for (int i = 0; i < 4; i++) {
                int idx = tid + i * 256;
                int kk = idx >> 6, n = idx & 63;
                int gc = ct + n;
                Bs[kk][n] = (gc < Tk) ? ztb[(size_t)(k0 + kk) * T_ + k + gc] : 0.f;
            }
            __syncthreads();
            #pragma unroll
            for (int kk = 0; kk < KT; kk++) {
                float a0 = Pst[k0 + kk][ty * 4 + 0], a1 = Pst[k0 + kk][ty * 4 + 1];
                float a2 = Pst[k0 + kk][ty * 4 + 2], a3 = Pst[k0 + kk][ty * 4 + 3];
                float4 bq = *(const float4*)&Bs[kk][tx * 4];
                acc[0][0] = fmaf(a0, bq.x, acc[0][0]); acc[0][1] = fmaf(a0, bq.y, acc[0][1]);
                acc[0][2] = fmaf(a0, bq.z, acc[0][2]); acc[0][3] = fmaf(a0, bq.w, acc[0][3]);
                acc[1][0] = fmaf(a1, bq.x, acc[1][0]); acc[1][1] = fmaf(a1, bq.y, acc[1][1]);
                acc[1][2] = fmaf(a1, bq.z, acc[1][2]); acc[1][3] = fmaf(a1, bq.w, acc[1][3]);
                acc[2][0] = fmaf(a2, bq.x, acc[2][0]); acc[2][1] = fmaf(a2, bq.y, acc[2][1]);
                acc[2][2] = fmaf(a2, bq.z, acc[2][2]); acc[2][3] = fmaf(a2, bq.w, acc[2][3]);
                acc[3][0] = fmaf(a3, bq.x, acc[3][0]); acc[3][1] = fmaf(a3, bq.y, acc[3][1]);
                acc[3][2] = fmaf(a3, bq.z, acc[3][2]); acc[3][3] = fmaf(a3, bq.w, acc[3][3]);
            }
            __syncthreads();
        }
        // online LSE update over this 64-col tile
        #pragma unroll
        for (int i = 0; i < 4; i++) {
            float l[4];
            float tmax = -INFINITY, tsum = 0.f;
            #pragma unroll
            for (int j = 0; j < 4; j++) {
                int gc = ct + tx * 4 + j;
                bool valid = gc < Tk;
                l[j] = valid ? acc[i][j] * INV_TEMP : -INFINITY;
                tmax = fmaxf(tmax, l[j]);
                tsum += valid ? l[j] : 0.f;
            }
            #pragma unroll
            for (int o = 1; o < 16; o <<= 1) {
                float ot = __shfl_xor(tmax, o, 64);
                tmax = fmaxf(tmax, ot);
            }
            float mnew = fmaxf(m[i], tmax);
            float e = 0.f;
            #pragma unroll
            for (int j = 0; j < 4; j++) e += expf(l[j] - mnew);
            #pragma unroll
            for (int o = 1; o < 16; o <<= 1) {
                e    += __shfl_xor(e, o, 64);
                tsum += __shfl_xor(tsum, o, 64);
            }
            s[i]  = s[i] * expf(m[i] - mnew) + e;
            m[i]  = mnew;
            sl[i] += tsum;
        }
    }
    // per-row value: LSE - mean(logits); sum valid rows
    float scale = 1.0f / ((float)K_ * (float)B_ * (float)Tk);
    float bs = 0.f;
    #pragma unroll
    for (int i = 0; i < 4; i++) {
        int gr = t0 + ty * 4 + i;
        if (gr < Tk) bs += m[i] + logf(s[i]) - sl[i] / (float)Tk;
    }
    if (tx != 0) bs = 0.f;
    bs = wave_sum(bs);
    if ((tid & 63) == 0) red[tid >> 6] = bs;
    __syncthreads();
    if (tid == 0)
        atomicAdd(&accum[(blockIdx.x * 809 + b * 67 + blockIdx.z * 131) & 1023],
                  (red[0] + red[1] + red[2] + red[3]) * scale);
}

__global__ void zero_accum(float* accum) { accum[threadIdx.x] = 0.f; }

__global__ void finalize(const float* __restrict__ accum, float* __restrict__ out) {
    int tid = threadIdx.x;
    __shared__ float red[4];
    float v = 0.f;
    for (int i = tid; i < 1024; i += 256) v += accum[i];
    float sres = wave_sum(v);
    if ((tid & 63) == 0) red[tid >> 6] = sres;
    __syncthreads();
    if (tid == 0) out[0] = red[0] + red[1] + red[2] + red[3];
}

// ---------------- launch -----------------------------------------------------
extern "C" void kernel_launch(void* const* d_in, const int* in_sizes, int n_in,
                              void* d_out, int out_size, void* d_ws, size_t ws_size,
                              hipStream_t stream) {
    const float* x      = (const float*)d_in[0];
    const float* W_enc  = (const float*)d_in[1];
    const float* b_enc  = (const float*)d_in[2];
    const float* W_proj = (const float*)d_in[3];
    const float* b_proj = (const float*)d_in[4];
    const float* Wi     = (const float*)d_in[5];
    const float* bi     = (const float*)d_in[6];
    const float* Wh     = (const float*)d_in[7];
    const float* bhn    = (const float*)d_in[8];
    const float* Wp     = (const float*)d_in[9];
    const float* bp     = (const float*)d_in[10];
    float* out = (float*)d_out;

    float* ws    = (float*)d_ws;
    float* Wc    = ws;                        // 32768
    float* bc    = Wc + 32768;                // 128
    float* accum = bc + 128;                  // 1024
    uint2* Whp   = (uint2*)(accum + 1024);    // 49152 uint2 = 98304 float-slots
    float* z     = accum + 1024 + 98304;      // B*T*P   = 4194304
    float* gi    = z + 4194304;               // B*T*3H  = 25165824
    float* c     = gi + 25165824;             // B*T*H   = 8388608
    float* zt    = gi;                        // aliases gi (dead after GRU): B*P*T

    const int MT = B_ * T_;                   // 32768

    zero_accum<<<1, 1024, 0, stream>>>(accum);
    fold_kernel<<<F_ + 1, P_, 0, stream>>>(W_enc, b_enc, W_proj, b_proj, Wc, bc);
    conv_whp<<<192, 256, 0, stream>>>(Wh, Whp);
    // z = x @ Wc + bc   (M=32768, N=128, K=256)
    gemm_bias<<<dim3(P_ / TS, MT / TS), 256, 0, stream>>>(x, Wc, bc, z, MT, P_, F_);
    // gi = z @ Wi + bi  (M=32768, N=768, K=128)
    gemm_bias<<<dim3(3 * H_ / TS, MT / TS), 256, 0, stream>>>(z, Wi, bi, gi, MT, 3 * H_, P_);
    // GRU scan
    gru_kernel<<<B_, 3 * H_, 0, stream>>>(gi, Whp, bhn, c);
    // transpose z for coalesced column access in the fused loss
    transpose_z<<<dim3(T_ / 32, P_ / 32, B_), 256, 0, stream>>>(z, zt);
    // fused pred-GEMM + flash loss, all k in one dispatch
    loss_fused<<<dim3(8, B_, K_), 256, 0, stream>>>(c, Wp, bp, zt, accum);
    finalize<<<1, 256, 0, stream>>>(accum, out);
}

// Round 4
// 6285.894 us; speedup vs baseline: 2.6980x; 1.2379x over previous
//
#include <hip/hip_runtime.h>
#include <hip/hip_bf16.h>
#include <math.h>

#define B_   64
#define T_   512
#define F_   256
#define ENC_ 256
#define P_   128
#define H_   256
#define K_   12
#define INV_TEMP 10.0f

typedef _Float16 half2v __attribute__((ext_vector_type(2)));
union U2H { unsigned int u; half2v h; };

// ---------------- helpers ----------------------------------------------------
__device__ __forceinline__ float dot2f16(unsigned int a, unsigned int b, float c) {
    U2H ua; ua.u = a; U2H ub; ub.u = b;
#if __has_builtin(__builtin_amdgcn_fdot2)
    return __builtin_amdgcn_fdot2(ua.h, ub.h, c, false);
#else
    return fmaf((float)ua.h.x, (float)ub.h.x, fmaf((float)ua.h.y, (float)ub.h.y, c));
#endif
}
__device__ __forceinline__ float wave_sum(float v) {
    #pragma unroll
    for (int o = 32; o > 0; o >>= 1) v += __shfl_down(v, o, 64);
    return v;
}

// ---------------- fold: Wc = W_enc @ W_proj, bc = b_enc @ W_proj + b_proj ----
__global__ void fold_kernel(const float* __restrict__ We, const float* __restrict__ be,
                            const float* __restrict__ Wp, const float* __restrict__ bp,
                            float* __restrict__ Wc, float* __restrict__ bc) {
    int f = blockIdx.x;      // 0..256 (256 == bias row)
    int p = threadIdx.x;     // 0..127
    if (f < F_) {
        float a = 0.f;
        for (int e = 0; e < ENC_; e++) a = fmaf(We[f * ENC_ + e], Wp[e * P_ + p], a);
        Wc[f * P_ + p] = a;
    } else {
        float a = bp[p];
        for (int e = 0; e < ENC_; e++) a = fmaf(be[e], Wp[e * P_ + p], a);
        bc[p] = a;
    }
}

// ---------------- Wh -> packed f16: Whh[i4*768+j] = rows 4i4..4i4+3 of col j -
__global__ void conv_whh(const float* __restrict__ Wh, uint2* __restrict__ Whh) {
    int idx = blockIdx.x * 256 + threadIdx.x;        // 49152 total
    int i4 = idx / 768, j = idx % 768;
    U2H lo, hi;
    lo.h.x = (_Float16)Wh[(size_t)(4 * i4 + 0) * 768 + j];
    lo.h.y = (_Float16)Wh[(size_t)(4 * i4 + 1) * 768 + j];
    hi.h.x = (_Float16)Wh[(size_t)(4 * i4 + 2) * 768 + j];
    hi.h.y = (_Float16)Wh[(size_t)(4 * i4 + 3) * 768 + j];
    Whh[idx] = make_uint2(lo.u, hi.u);
}

// ---------------- generic tiled f32 GEMM: C = A(MxK) @ B(KxN) + bias ---------
#define TS 64
#define KT 16
__global__ __launch_bounds__(256) void gemm_bias(const float* __restrict__ A,
                                                 const float* __restrict__ Bm,
                                                 const float* __restrict__ bias,
                                                 float* __restrict__ C,
                                                 int M, int N, int K) {
    __shared__ float As[KT][TS + 1];
    __shared__ float Bs[KT][TS];
    int tid = threadIdx.x;
    int bm = blockIdx.y * TS, bn = blockIdx.x * TS;
    int tx = tid & 15, ty = tid >> 4;
    float acc[4][4] = {};
    for (int k0 = 0; k0 < K; k0 += KT) {
        #pragma unroll
        for (int i = 0; i < 4; i++) {
            int idx = tid + i * 256;
            int m = idx >> 4, kk = idx & 15;
            int gm = bm + m;
            As[kk][m] = (gm < M) ? A[(size_t)gm * K + k0 + kk] : 0.f;
        }
        #pragma unroll
        for (int i = 0; i < 4; i++) {
            int idx = tid + i * 256;
            int kk = idx >> 6, n = idx & 63;
            Bs[kk][n] = Bm[(size_t)(k0 + kk) * N + bn + n];
        }
        __syncthreads();
        #pragma unroll
        for (int kk = 0; kk < KT; kk++) {
            float a0 = As[kk][ty * 4 + 0], a1 = As[kk][ty * 4 + 1];
            float a2 = As[kk][ty * 4 + 2], a3 = As[kk][ty * 4 + 3];
            float4 bq = *(const float4*)&Bs[kk][tx * 4];
            acc[0][0] = fmaf(a0, bq.x, acc[0][0]); acc[0][1] = fmaf(a0, bq.y, acc[0][1]);
            acc[0][2] = fmaf(a0, bq.z, acc[0][2]); acc[0][3] = fmaf(a0, bq.w, acc[0][3]);
            acc[1][0] = fmaf(a1, bq.x, acc[1][0]); acc[1][1] = fmaf(a1, bq.y, acc[1][1]);
            acc[1][2] = fmaf(a1, bq.z, acc[1][2]); acc[1][3] = fmaf(a1, bq.w, acc[1][3]);
            acc[2][0] = fmaf(a2, bq.x, acc[2][0]); acc[2][1] = fmaf(a2, bq.y, acc[2][1]);
            acc[2][2] = fmaf(a2, bq.z, acc[2][2]); acc[2][3] = fmaf(a2, bq.w, acc[2][3]);
            acc[3][0] = fmaf(a3, bq.x, acc[3][0]); acc[3][1] = fmaf(a3, bq.y, acc[3][1]);
            acc[3][2] = fmaf(a3, bq.z, acc[3][2]); acc[3][3] = fmaf(a3, bq.w, acc[3][3]);
        }
        __syncthreads();
    }
    #pragma unroll
    for (int i = 0; i < 4; i++) {
        int gm = bm + ty * 4 + i;
        if (gm >= M) continue;
        #pragma unroll
        for (int j = 0; j < 4; j++) {
            int gn = bn + tx * 4 + j;
            C[(size_t)gm * N + gn] = acc[i][j] + (bias ? bias[gn] : 0.f);
        }
    }
}

// ---------------- GRU scan: 256 threads/block, 1 block per batch -------------
// Thread j owns gate columns j (r), j+256 (z), j+512 (n): all gate math is
// thread-local, ONE barrier per step. All 3*256 f16 weights live in 384 VGPRs
// (waves_per_eu(1,1) -> 512-VGPR budget; asm pin prevents load sinking).
// h crosses threads as packed f16 in LDS (double-buffered); the j-th element's
// recurrence stays fp32 in a register.
__global__ __attribute__((amdgpu_flat_work_group_size(256, 256), amdgpu_waves_per_eu(1, 1)))
void gru_kernel(const float* __restrict__ gi,
                const uint2* __restrict__ Whh,
                const float* __restrict__ bhn,
                float* __restrict__ c_seq) {
    int b = blockIdx.x;
    int j = threadIdx.x;                 // 0..255
    __shared__ uint2 hbuf[2][64];        // 2 x 256 f16 h values

    uint2 wR[64], wZ[64], wN[64];
    {
        const uint2* cR = Whh + j;
        const uint2* cZ = Whh + 256 + j;
        const uint2* cN = Whh + 512 + j;
        #pragma unroll
        for (int i = 0; i < 64; i++) {
            wR[i] = cR[(size_t)i * 768];
            wZ[i] = cZ[(size_t)i * 768];
            wN[i] = cN[(size_t)i * 768];
        }
    }
    #pragma unroll
    for (int i = 0; i < 64; i++) {
        asm volatile("" : "+v"(wR[i].x), "+v"(wR[i].y));
        asm volatile("" : "+v"(wZ[i].x), "+v"(wZ[i].y));
        asm volatile("" : "+v"(wN[i].x), "+v"(wN[i].y));
    }
    ((_Float16*)hbuf)[j] = (_Float16)0.f;    // hbuf[0] = 0
    float bh = bhn[j];
    float hloc = 0.f;
    __syncthreads();

    const float* gib = gi + (size_t)b * T_ * 768;
    float* cb = c_seq + (size_t)b * T_ * H_;
    int cur = 0;
    for (int t = 0; t < T_; t++) {
        const float* gt = gib + (size_t)t * 768;
        float ir  = gt[j];
        float iz  = gt[256 + j];
        float inn = gt[512 + j];
        const uint2* h4 = hbuf[cur];
        float ar0 = 0.f, ar1 = 0.f, az0 = 0.f, az1 = 0.f, an0 = 0.f, an1 = 0.f;
        #pragma unroll
        for (int i = 0; i < 64; i++) {
            uint2 hv = h4[i];
            ar0 = dot2f16(hv.x, wR[i].x, ar0);
            ar1 = dot2f16(hv.y, wR[i].y, ar1);
            az0 = dot2f16(hv.x, wZ[i].x, az0);
            az1 = dot2f16(hv.y, wZ[i].y, az1);
            an0 = dot2f16(hv.x, wN[i].x, an0);
            an1 = dot2f16(hv.y, wN[i].y, an1);
        }
        float r  = 1.f / (1.f + expf(-(ir + ar0 + ar1)));
        float zg = 1.f / (1.f + expf(-(iz + az0 + az1)));
        float n  = tanhf(inn + r * (an0 + an1 + bh));
        hloc = (1.f - zg) * n + zg * hloc;
        cb[(size_t)t * H_ + j] = hloc;
        ((_Float16*)hbuf)[(cur ^ 1) * 256 + j] = (_Float16)hloc;
        __syncthreads();
        cur ^= 1;
    }
}

// ---------------- transpose z (BxTxP) -> zt (BxPxT) --------------------------
__global__ __launch_bounds__(256) void transpose_z(const float* __restrict__ z,
                                                   float* __restrict__ zt) {
    __shared__ float tile[32][33];
    int b = blockIdx.z;
    int t0 = blockIdx.x * 32, d0 = blockIdx.y * 32;
    int tx = threadIdx.x & 31, ty = threadIdx.x >> 5;   // 32 x 8
    #pragma unroll
    for (int i = 0; i < 32; i += 8)
        tile[ty + i][tx] = z[((size_t)b * T_ + t0 + ty + i) * P_ + d0 + tx];
    __syncthreads();
    #pragma unroll
    for (int i = 0; i < 32; i += 8)
        zt[((size_t)b * P_ + d0 + ty + i) * T_ + t0 + tx] = tile[tx][ty + i];
}

// ---------------- fused loss: pred tile GEMM + flash LSE, all k in one grid --
__global__ __launch_bounds__(256) void loss_fused(const float* __restrict__ c,
                                                  const float* __restrict__ Wp,
                                                  const float* __restrict__ bp,
                                                  const float* __restrict__ zt,
                                                  float* __restrict__ accum) {
    __shared__ float Pst[P_][TS + 1];    // pred^T: [k-dim 128][row 64]
    __shared__ float As[KT][TS + 1];
    __shared__ float Bs[KT][2 * TS];
    __shared__ float red[4];
    int k  = blockIdx.z + 1;
    int b  = blockIdx.y;
    int t0 = blockIdx.x * TS;
    int Tk = T_ - k;
    int tid = threadIdx.x;

    // ---- phase 1: pred tile (64 rows x 128 cols), microtile 4x8 -------------
    {
        int tx = tid & 15, ty = tid >> 4;
        float acc[4][8] = {};
        const float* cb  = c + ((size_t)b * T_ + t0) * H_;
        const float* wpk = Wp + (size_t)(k - 1) * H_ * P_;
        for (int k0 = 0; k0 < H_; k0 += KT) {
            #pragma unroll
            for (int i = 0; i < 4; i++) {
                int idx = tid + i * 256;
                int mm = idx >> 4, kk = idx & 15;
                As[kk][mm] = cb[(size_t)mm * H_ + k0 + kk];
            }
            #pragma unroll
            for (int i = 0; i < 8; i++) {
                int idx = tid + i * 256;
                int kk = idx >> 7, n = idx & 127;
                Bs[kk][n] = wpk[(size_t)(k0 + kk) * P_ + n];
            }
            __syncthreads();
            #pragma unroll
            for (int kk = 0; kk < KT; kk++) {
                float a0 = As[kk][ty * 4 + 0], a1 = As[kk][ty * 4 + 1];
                float a2 = As[kk][ty * 4 + 2], a3 = As[kk][ty * 4 + 3];
                float4 b0 = *(const float4*)&Bs[kk][tx * 8];
                float4 b1 = *(const float4*)&Bs[kk][tx * 8 + 4];
                acc[0][0] = fmaf(a0, b0.x, acc[0][0]); acc[0][1] = fmaf(a0, b0.y, acc[0][1]);
                acc[0][2] = fmaf(a0, b0.z, acc[0][2]); acc[0][3] = fmaf(a0, b0.w, acc[0][3]);
                acc[0][4] = fmaf(a0, b1.x, acc[0][4]); acc[0][5] = fmaf(a0, b1.y, acc[0][5]);
                acc[0][6] = fmaf(a0, b1.z, acc[0][6]); acc[0][7] = fmaf(a0, b1.w, acc[0][7]);
                acc[1][0] = fmaf(a1, b0.x, acc[1][0]); acc[1][1] = fmaf(a1, b0.y, acc[1][1]);
                acc[1][2] = fmaf(a1, b0.z, acc[1][2]); acc[1][3] = fmaf(a1, b0.w, acc[1][3]);
                acc[1][4] = fmaf(a1, b1.x, acc[1][4]); acc[1][5] = fmaf(a1, b1.y, acc[1][5]);
                acc[1][6] = fmaf(a1, b1.z, acc[1][6]); acc[1][7] = fmaf(a1, b1.w, acc[1][7]);
                acc[2][0] = fmaf(a2, b0.x, acc[2][0]); acc[2][1] = fmaf(a2, b0.y, acc[2][1]);
                acc[2][2] = fmaf(a2, b0.z, acc[2][2]); acc[2][3] = fmaf(a2, b0.w, acc[2][3]);
                acc[2][4] = fmaf(a2, b1.x, acc[2][4]); acc[2][5] = fmaf(a2, b1.y, acc[2][5]);
                acc[2][6] = fmaf(a2, b1.z, acc[2][6]); acc[2][7] = fmaf(a2, b1.w, acc[2][7]);
                acc[3][0] = fmaf(a3, b0.x, acc[3][0]); acc[3][1] = fmaf(a3, b0.y, acc[3][1]);
                acc[3][2] = fmaf(a3, b0.z, acc[3][2]); acc[3][3] = fmaf(a3, b0.w, acc[3][3]);
                acc[3][4] = fmaf(a3, b1.x, acc[3][4]); acc[3][5] = fmaf(a3, b1.y, acc[3][5]);
                acc[3][6] = fmaf(a3, b1.z, acc[3][6]); acc[3][7] = fmaf(a3, b1.w, acc[3][7]);
            }
            __syncthreads();
        }
        #pragma unroll
        for (int jj = 0; jj < 8; jj++) {
            float bias = bp[(size_t)(k - 1) * P_ + tx * 8 + jj];
            #pragma unroll
            for (int i = 0; i < 4; i++)
                Pst[tx * 8 + jj][ty * 4 + i] = acc[i][jj] + bias;
        }
    }
    __syncthreads();

    // ---- phase 2: flash over column tiles -----------------------------------
    int tx = tid & 15, ty = tid >> 4;
    float m[4], s[4], sl[4];
    #pragma unroll
    for (int i = 0; i < 4; i++) { m[i] = -INFINITY; s[i] = 0.f; sl[i] = 0.f; }
    const float* ztb = zt + (size_t)b * P_ * T_;

    for (int ct = 0; ct < Tk; ct += TS) {
        float acc[4][4] = {};
        for (int k0 = 0; k0 < P_; k0 += KT) {
            #pragma unroll
            for (int i = 0; i < 4; i++) {
                int idx = tid + i * 256;
                int kk = idx >> 6, n = idx & 63;
                int gc = ct + n;
                Bs[kk][n] = (gc < Tk) ? ztb[(size_t)(k0 + kk) * T_ + k + gc] : 0.f;
            }
            __syncthreads();
            #pragma unroll
            for (int kk = 0; kk < KT; kk++) {
                float a0 = Pst[k0 + kk][ty * 4 + 0], a1 = Pst[k0 + kk][ty * 4 + 1];
                float a2 = Pst[k0 + kk][ty * 4 + 2], a3 = Pst[k0 + kk][ty * 4 + 3];
                float4 bq = *(const float4*)&Bs[kk][tx * 4];
                acc[0][0] = fmaf(a0, bq.x, acc[0][0]); acc[0][1] = fmaf(a0, bq.y, acc[0][1]);
                acc[0][2] = fmaf(a0, bq.z, acc[0][2]); acc[0][3] = fmaf(a0, bq.w, acc[0][3]);
                acc[1][0] = fmaf(a1, bq.x, acc[1][0]); acc[1][1] = fmaf(a1, bq.y, acc[1][1]);
                acc[1][2] = fmaf(a1, bq.z, acc[1][2]); acc[1][3] = fmaf(a1, bq.w, acc[1][3]);
                acc[2][0] = fmaf(a2, bq.x, acc[2][0]); acc[2][1] = fmaf(a2, bq.y, acc[2][1]);
                acc[2][2] = fmaf(a2, bq.z, acc[2][2]); acc[2][3] = fmaf(a2, bq.w, acc[2][3]);
                acc[3][0] = fmaf(a3, bq.x, acc[3][0]); acc[3][1] = fmaf(a3, bq.y, acc[3][1]);
                acc[3][2] = fmaf(a3, bq.z, acc[3][2]); acc[3][3] = fmaf(a3, bq.w, acc[3][3]);
            }
            __syncthreads();
        }
        #pragma unroll
        for (int i = 0; i < 4; i++) {
            float l[4];
            float tmax = -INFINITY, tsum = 0.f;
            #pragma unroll
            for (int j = 0; j < 4; j++) {
                int gc = ct + tx * 4 + j;
                bool valid = gc < Tk;
                l[j] = valid ? acc[i][j] * INV_TEMP : -INFINITY;
                tmax = fmaxf(tmax, l[j]);
                tsum += valid ? l[j] : 0.f;
            }
            #pragma unroll
            for (int o = 1; o < 16; o <<= 1) {
                float ot = __shfl_xor(tmax, o, 64);
                tmax = fmaxf(tmax, ot);
            }
            float mnew = fmaxf(m[i], tmax);
            float e = 0.f;
            #pragma unroll
            for (int j = 0; j < 4; j++) e += expf(l[j] - mnew);
            #pragma unroll
            for (int o = 1; o < 16; o <<= 1) {
                e    += __shfl_xor(e, o, 64);
                tsum += __shfl_xor(tsum, o, 64);
            }
            s[i]  = s[i] * expf(m[i] - mnew) + e;
            m[i]  = mnew;
            sl[i] += tsum;
        }
    }
    float scale = 1.0f / ((float)K_ * (float)B_ * (float)Tk);
    float bs = 0.f;
    #pragma unroll
    for (int i = 0; i < 4; i++) {
        int gr = t0 + ty * 4 + i;
        if (gr < Tk) bs += m[i] + logf(s[i]) - sl[i] / (float)Tk;
    }
    if (tx != 0) bs = 0.f;
    bs = wave_sum(bs);
    if ((tid & 63) == 0) red[tid >> 6] = bs;
    __syncthreads();
    if (tid == 0)
        atomicAdd(&accum[(blockIdx.x * 809 + b * 67 + blockIdx.z * 131) & 1023],
                  (red[0] + red[1] + red[2] + red[3]) * scale);
}

__global__ void zero_accum(float* accum) { accum[threadIdx.x] = 0.f; }

__global__ void finalize(const float* __restrict__ accum, float* __restrict__ out) {
    int tid = threadIdx.x;
    __shared__ float red[4];
    float v = 0.f;
    for (int i = tid; i < 1024; i += 256) v += accum[i];
    float sres = wave_sum(v);
    if ((tid & 63) == 0) red[tid >> 6] = sres;
    __syncthreads();
    if (tid == 0) out[0] = red[0] + red[1] + red[2] + red[3];
}

// ---------------- launch -----------------------------------------------------
extern "C" void kernel_launch(void* const* d_in, const int* in_sizes, int n_in,
                              void* d_out, int out_size, void* d_ws, size_t ws_size,
                              hipStream_t stream) {
    const float* x      = (const float*)d_in[0];
    const float* W_enc  = (const float*)d_in[1];
    const float* b_enc  = (const float*)d_in[2];
    const float* W_proj = (const float*)d_in[3];
    const float* b_proj = (const float*)d_in[4];
    const float* Wi     = (const float*)d_in[5];
    const float* bi     = (const float*)d_in[6];
    const float* Wh     = (const float*)d_in[7];
    const float* bhn    = (const float*)d_in[8];
    const float* Wp     = (const float*)d_in[9];
    const float* bp     = (const float*)d_in[10];
    float* out = (float*)d_out;

    float* ws    = (float*)d_ws;
    float* Wc    = ws;                        // 32768
    float* bc    = Wc + 32768;                // 128
    float* accum = bc + 128;                  // 1024
    uint2* Whh   = (uint2*)(accum + 1024);    // 49152 uint2 = 98304 float-slots
    float* z     = accum + 1024 + 98304;      // B*T*P   = 4194304
    float* gi    = z + 4194304;               // B*T*3H  = 25165824
    float* c     = gi + 25165824;             // B*T*H   = 8388608
    float* zt    = gi;                        // aliases gi (dead after GRU): B*P*T

    const int MT = B_ * T_;                   // 32768

    zero_accum<<<1, 1024, 0, stream>>>(accum);
    fold_kernel<<<F_ + 1, P_, 0, stream>>>(W_enc, b_enc, W_proj, b_proj, Wc, bc);
    conv_whh<<<192, 256, 0, stream>>>(Wh, Whh);
    // z = x @ Wc + bc   (M=32768, N=128, K=256)
    gemm_bias<<<dim3(P_ / TS, MT / TS), 256, 0, stream>>>(x, Wc, bc, z, MT, P_, F_);
    // gi = z @ Wi + bi  (M=32768, N=768, K=128)
    gemm_bias<<<dim3(3 * H_ / TS, MT / TS), 256, 0, stream>>>(z, Wi, bi, gi, MT, 3 * H_, P_);
    // GRU scan: 256 threads, full weight residency in VGPRs
    gru_kernel<<<B_, 256, 0, stream>>>(gi, Whh, bhn, c);
    // transpose z for coalesced column access in the fused loss
    transpose_z<<<dim3(T_ / 32, P_ / 32, B_), 256, 0, stream>>>(z, zt);
    // fused pred-GEMM + flash loss, all k in one dispatch
    loss_fused<<<dim3(8, B_, K_), 256, 0, stream>>>(c, Wp, bp, zt, accum);
    finalize<<<1, 256, 0, stream>>>(accum, out);
}